// Round 1
// baseline (14939.432 us; speedup 1.0000x reference)
//
#include <hip/hip_runtime.h>

#define T_STEPS 512
#define BB 64
#define EE 300
#define EP 320
#define HH 512
#define G3 1536
#define HB (BB*HH)   // halves per h buffer

typedef _Float16 f16x8 __attribute__((ext_vector_type(8)));
typedef float f32x4 __attribute__((ext_vector_type(4)));

__device__ __forceinline__ f32x4 mf(f16x8 a, f16x8 b, f32x4 c) {
  return __builtin_amdgcn_mfma_f32_16x16x32_f16(a, b, c, 0, 0, 0);
}

// agent-scope (cross-XCD coherent) 16B fragment load
__device__ __forceinline__ f16x8 ld_frag_agent(const _Float16* p) {
  union { unsigned long long u[2]; f16x8 v; } x;
  const unsigned long long* q = (const unsigned long long*)p;
  x.u[0] = __hip_atomic_load(q,     __ATOMIC_RELAXED, __HIP_MEMORY_SCOPE_AGENT);
  x.u[1] = __hip_atomic_load(q + 1, __ATOMIC_RELAXED, __HIP_MEMORY_SCOPE_AGENT);
  return x.v;
}

__device__ __forceinline__ float ld_h_agent(const _Float16* p) {
  unsigned short u = __hip_atomic_load((const unsigned short*)p, __ATOMIC_RELAXED, __HIP_MEMORY_SCOPE_AGENT);
  _Float16 h;
  __builtin_memcpy(&h, &u, 2);
  return (float)h;
}

__device__ __forceinline__ void st_h_agent(_Float16* p, float v) {
  _Float16 h = (_Float16)v;
  unsigned short u;
  __builtin_memcpy(&u, &h, 2);
  __hip_atomic_store((unsigned short*)p, u, __ATOMIC_RELAXED, __HIP_MEMORY_SCOPE_AGENT);
}

__device__ __forceinline__ float sigf(float x) { return 1.f / (1.f + __expf(-x)); }

struct B3 { f16x8 r, z, n; };
// W row-major [1536][K]; rows g*512 + j; loads the 3 gate rows for this lane
__device__ __forceinline__ B3 ldB(const _Float16* __restrict__ W, int K, int row0, int koff) {
  B3 o;
  const _Float16* p = W + (size_t)row0 * K + koff;
  o.r = *(const f16x8*)p;
  o.z = *(const f16x8*)(p + (size_t)512 * K);
  o.n = *(const f16x8*)(p + (size_t)1024 * K);
  return o;
}

__global__ void prep_x0(const int* __restrict__ texts, const float* __restrict__ emb,
                        _Float16* __restrict__ x0) {
  const size_t N = (size_t)T_STEPS * BB * EP;
  const size_t stride = (size_t)gridDim.x * blockDim.x;
  for (size_t i = (size_t)blockIdx.x * blockDim.x + threadIdx.x; i < N; i += stride) {
    int e = (int)(i % EP);
    size_t tb = i / EP;
    float v = 0.f;
    if (e < EE) v = emb[(size_t)texts[tb] * EE + e];
    x0[i] = (_Float16)v;
  }
}

__global__ void prep_w(const float* __restrict__ Wih0, const float* __restrict__ Whh0,
                       const float* __restrict__ bih0, const float* __restrict__ bhh0,
                       const float* __restrict__ Wih1, const float* __restrict__ Whh1,
                       const float* __restrict__ bih1, const float* __restrict__ bhh1,
                       _Float16* __restrict__ W0x, _Float16* __restrict__ W0h,
                       _Float16* __restrict__ W1x, _Float16* __restrict__ W1h,
                       float* __restrict__ bias0, float* __restrict__ bias1) {
  const size_t stride = (size_t)gridDim.x * blockDim.x;
  const size_t gid = (size_t)blockIdx.x * blockDim.x + threadIdx.x;
  for (size_t i = gid; i < (size_t)G3 * EP; i += stride) {
    int k = (int)(i % EP); int n = (int)(i / EP);
    W0x[i] = (k < EE) ? (_Float16)Wih0[(size_t)n * EE + k] : (_Float16)0.f;
  }
  for (size_t i = gid; i < (size_t)G3 * HH; i += stride) {
    W0h[i] = (_Float16)Whh0[i];
    W1x[i] = (_Float16)Wih1[i];
    W1h[i] = (_Float16)Whh1[i];
  }
  for (size_t i = gid; i < (size_t)HH; i += stride) {
    bias0[i]        = bih0[i] + bhh0[i];
    bias0[512 + i]  = bih0[512 + i] + bhh0[512 + i];
    bias0[1024 + i] = bih0[1024 + i];
    bias0[1536 + i] = bhh0[1024 + i];
    bias1[i]        = bih1[i] + bhh1[i];
    bias1[512 + i]  = bih1[512 + i] + bhh1[512 + i];
    bias1[1024 + i] = bih1[1024 + i];
    bias1[1536 + i] = bhh1[1024 + i];
  }
}

// 64 WGs x 256 threads. WG 0..31: layer0 j-chunks; WG 32..63: layer1 j-chunks.
// Stage s: L0 computes h1[s] (s<512); L1 computes h2[s-1] (s>=1). Barrier per stage.
__global__ __launch_bounds__(256, 1) void gru_persistent(
    const _Float16* __restrict__ x0,
    const _Float16* __restrict__ W0x, const _Float16* __restrict__ W0h,
    const _Float16* __restrict__ W1x, const _Float16* __restrict__ W1h,
    const float* __restrict__ bias0, const float* __restrict__ bias1,
    _Float16* h1buf, _Float16* h2buf, float* pooled, int* arrive)
{
  const int wg   = blockIdx.x;
  const int L    = wg >> 5;
  const int jb   = (wg & 31) * 16;
  const int tid  = threadIdx.x;
  const int bsub = tid >> 6;
  const int lane = tid & 63;
  const int quad = lane >> 4;
  const int l15  = lane & 15;
  const int brow = bsub * 16 + l15;   // A-operand row (batch) this lane loads
  const int j    = jb + l15;          // output column (gate col) this lane owns
  const int koff = quad * 8;

  __shared__ float lds[4][4][16];

  for (int s = 0; s <= T_STEPS; ++s) {
    if (L == 0) {
      if (s < T_STEPS) {
        const _Float16* h1p = h1buf + ((s + 1) & 1) * HB;   // h1[s-1]
        f16x8 hA[16];
        #pragma unroll
        for (int c = 0; c < 16; ++c)
          hA[c] = ld_frag_agent(h1p + brow * HH + c * 32 + koff);

        f32x4 aR = {0.f,0.f,0.f,0.f}, aZ = {0.f,0.f,0.f,0.f};
        f32x4 aNX = {0.f,0.f,0.f,0.f}, aNH = {0.f,0.f,0.f,0.f};
        const _Float16* xr = x0 + ((size_t)s * BB + brow) * EP;
        #pragma unroll 2
        for (int c = 0; c < 10; ++c) {
          f16x8 a = *(const f16x8*)(xr + c * 32 + koff);
          B3 bb = ldB(W0x, EP, j, c * 32 + koff);
          aR = mf(a, bb.r, aR); aZ = mf(a, bb.z, aZ); aNX = mf(a, bb.n, aNX);
        }
        #pragma unroll 2
        for (int c = 0; c < 16; ++c) {
          B3 bb = ldB(W0h, HH, j, c * 32 + koff);
          aR = mf(hA[c], bb.r, aR); aZ = mf(hA[c], bb.z, aZ); aNH = mf(hA[c], bb.n, aNH);
        }

        _Float16* h1n = h1buf + (s & 1) * HB;
        const float br = bias0[j], bz = bias0[512 + j];
        const float bnx = bias0[1024 + j], bnh = bias0[1536 + j];
        #pragma unroll
        for (int rg = 0; rg < 4; ++rg) {
          const int b = bsub * 16 + quad * 4 + rg;   // C/D row = quad*4+reg
          float r = sigf(aR[rg] + br);
          float z = sigf(aZ[rg] + bz);
          float n = tanhf(aNX[rg] + bnx + r * (aNH[rg] + bnh));
          float hp = ld_h_agent(h1p + b * HH + j);
          st_h_agent(h1n + b * HH + j, (1.f - z) * n + z * hp);
        }
      }
    } else {
      if (s >= 1) {
        const _Float16* a1p = h1buf + ((s + 1) & 1) * HB;   // h1[s-1] (layer-1 input)
        const _Float16* h2p = h2buf + (s & 1) * HB;         // h2[s-2]
        f16x8 A1[16], A2[16];
        #pragma unroll
        for (int c = 0; c < 16; ++c) {
          A1[c] = ld_frag_agent(a1p + brow * HH + c * 32 + koff);
          A2[c] = ld_frag_agent(h2p + brow * HH + c * 32 + koff);
        }
        f32x4 aR = {0.f,0.f,0.f,0.f}, aZ = {0.f,0.f,0.f,0.f};
        f32x4 aNX = {0.f,0.f,0.f,0.f}, aNH = {0.f,0.f,0.f,0.f};
        #pragma unroll 2
        for (int c = 0; c < 16; ++c) {
          B3 bb = ldB(W1x, HH, j, c * 32 + koff);
          aR = mf(A1[c], bb.r, aR); aZ = mf(A1[c], bb.z, aZ); aNX = mf(A1[c], bb.n, aNX);
        }
        #pragma unroll 2
        for (int c = 0; c < 16; ++c) {
          B3 bb = ldB(W1h, HH, j, c * 32 + koff);
          aR = mf(A2[c], bb.r, aR); aZ = mf(A2[c], bb.z, aZ); aNH = mf(A2[c], bb.n, aNH);
        }
        _Float16* h2n = h2buf + ((s + 1) & 1) * HB;   // h2[s-1]
        const float br = bias1[j], bz = bias1[512 + j];
        const float bnx = bias1[1024 + j], bnh = bias1[1536 + j];
        float psum = 0.f;
        #pragma unroll
        for (int rg = 0; rg < 4; ++rg) {
          const int b = bsub * 16 + quad * 4 + rg;
          float r = sigf(aR[rg] + br);
          float z = sigf(aZ[rg] + bz);
          float n = tanhf(aNX[rg] + bnx + r * (aNH[rg] + bnh));
          float hp = ld_h_agent(h2p + b * HH + j);
          float hn = (1.f - z) * n + z * hp;
          st_h_agent(h2n + b * HH + j, hn);
          psum += hn;
        }
        lds[bsub][quad][l15] = psum;
        __syncthreads();
        if (tid < 16) {
          float tot = 0.f;
          #pragma unroll
          for (int a = 0; a < 4; ++a)
            #pragma unroll
            for (int q = 0; q < 4; ++q) tot += lds[a][q][tid];
          pooled[(size_t)(s - 1) * HH + jb + tid] = tot;   // raw sum over b; /64 in FC
        }
      }
    }

    // per-stage grid barrier (own counter per stage; no reset hazard)
    __syncthreads();   // drains all waves' stores (vmcnt 0) before arrival
    if (tid == 0) {
      __hip_atomic_fetch_add(&arrive[s], 1, __ATOMIC_RELEASE, __HIP_MEMORY_SCOPE_AGENT);
      while (__hip_atomic_load(&arrive[s], __ATOMIC_RELAXED, __HIP_MEMORY_SCOPE_AGENT) < 64)
        __builtin_amdgcn_s_sleep(1);
      (void)__hip_atomic_load(&arrive[s], __ATOMIC_ACQUIRE, __HIP_MEMORY_SCOPE_AGENT);
    }
    __syncthreads();
  }
}

__global__ void fc_kernel(const float* __restrict__ pooled, const float* __restrict__ fcW,
                          const float* __restrict__ fcb, float* __restrict__ out) {
  const int t = blockIdx.x;
  const int lane = threadIdx.x;  // 64 = one wave
  float a0 = 0.f, a1 = 0.f, a2 = 0.f, a3 = 0.f, a4 = 0.f;
  for (int jj = lane; jj < HH; jj += 64) {
    float p = pooled[(size_t)t * HH + jj];
    a0 += p * fcW[jj];
    a1 += p * fcW[512 + jj];
    a2 += p * fcW[1024 + jj];
    a3 += p * fcW[1536 + jj];
    a4 += p * fcW[2048 + jj];
  }
  #pragma unroll
  for (int off = 32; off > 0; off >>= 1) {
    a0 += __shfl_down(a0, off, 64);
    a1 += __shfl_down(a1, off, 64);
    a2 += __shfl_down(a2, off, 64);
    a3 += __shfl_down(a3, off, 64);
    a4 += __shfl_down(a4, off, 64);
  }
  if (lane == 0) {
    const float sc = 1.f / 64.f;
    out[t * 5 + 0] = a0 * sc + fcb[0];
    out[t * 5 + 1] = a1 * sc + fcb[1];
    out[t * 5 + 2] = a2 * sc + fcb[2];
    out[t * 5 + 3] = a3 * sc + fcb[3];
    out[t * 5 + 4] = a4 * sc + fcb[4];
  }
}

extern "C" void kernel_launch(void* const* d_in, const int* in_sizes, int n_in,
                              void* d_out, int out_size, void* d_ws, size_t ws_size,
                              hipStream_t stream) {
  const int*   texts = (const int*)  d_in[0];
  const float* emb   = (const float*)d_in[1];
  const float* Wih0  = (const float*)d_in[2];
  const float* Whh0  = (const float*)d_in[3];
  const float* bih0  = (const float*)d_in[4];
  const float* bhh0  = (const float*)d_in[5];
  const float* Wih1  = (const float*)d_in[6];
  const float* Whh1  = (const float*)d_in[7];
  const float* bih1  = (const float*)d_in[8];
  const float* bhh1  = (const float*)d_in[9];
  const float* fcW   = (const float*)d_in[10];
  const float* fcb   = (const float*)d_in[11];
  float* out = (float*)d_out;

  char* ws = (char*)d_ws;
  int*      arrive = (int*)ws;                       // 4096 B
  _Float16* h1buf  = (_Float16*)(ws + 4096);         // 131072 B (2x64x512 f16)
  _Float16* h2buf  = (_Float16*)(ws + 135168);       // 131072 B
  _Float16* x0     = (_Float16*)(ws + 266240);       // 20971520 B [512][64][320]
  _Float16* W0x    = (_Float16*)(ws + 21237760);     // 983040 B  [1536][320]
  _Float16* W0h    = (_Float16*)(ws + 22220800);     // 1572864 B [1536][512]
  _Float16* W1x    = (_Float16*)(ws + 23793664);     // 1572864 B
  _Float16* W1h    = (_Float16*)(ws + 25366528);     // 1572864 B
  float*    bias0  = (float*)(ws + 26939392);        // 8192 B (r,z,nx,nh)
  float*    bias1  = (float*)(ws + 26947584);        // 8192 B
  float*    pooled = (float*)(ws + 26955776);        // 1048576 B [512][512] f32
  // total ws use: 28004352 B

  hipMemsetAsync(ws, 0, 266240, stream);  // arrive + h1 + h2 = zeros
  prep_x0<<<4096, 256, 0, stream>>>(texts, emb, x0);
  prep_w<<<1024, 256, 0, stream>>>(Wih0, Whh0, bih0, bhh0, Wih1, Whh1, bih1, bhh1,
                                   W0x, W0h, W1x, W1h, bias0, bias1);
  gru_persistent<<<64, 256, 0, stream>>>(x0, W0x, W0h, W1x, W1h, bias0, bias1,
                                         h1buf, h2buf, pooled, arrive);
  fc_kernel<<<512, 64, 0, stream>>>(pooled, fcW, fcb, out);
}

// Round 2
// 14930.785 us; speedup vs baseline: 1.0006x; 1.0006x over previous
//
#include <hip/hip_runtime.h>

#define T_STEPS 512
#define BB 64
#define EE 300
#define EP 320
#define HH 512
#define G3 1536
#define HB (BB*HH)   // halves per h slot
#define RING 4

typedef _Float16 f16x8 __attribute__((ext_vector_type(8)));
typedef float f32x4 __attribute__((ext_vector_type(4)));
typedef int i32x4 __attribute__((ext_vector_type(4)));

#define MEMBAR() asm volatile("" ::: "memory")

__device__ __forceinline__ f32x4 mf(f16x8 a, f16x8 b, f32x4 c) {
  return __builtin_amdgcn_mfma_f32_16x16x32_f16(a, b, c, 0, 0, 0);
}

// LLC-coherent (cross-XCD) 8B load; relaxed agent scope -> sc1 bypass of L1/L2
__device__ __forceinline__ unsigned long long ld8_llc(const unsigned long long* p) {
  return __hip_atomic_load(p, __ATOMIC_RELAXED, __HIP_MEMORY_SCOPE_AGENT);
}

// LLC-coherent 16B store (coalesced; stores need no result tracking, waitcnt(0) drains)
__device__ __forceinline__ void st16_llc(void* p, f16x8 v) {
  i32x4 iv;
  __builtin_memcpy(&iv, &v, 16);
  asm volatile("global_store_dwordx4 %0, %1, off sc0 sc1" :: "v"(p), "v"(iv) : "memory");
}

__device__ __forceinline__ void spin_ge(const int* a, int tgt) {
  while (__hip_atomic_load(a, __ATOMIC_RELAXED, __HIP_MEMORY_SCOPE_AGENT) < tgt) {}
}

__device__ __forceinline__ float sigf(float x) { return 1.f / (1.f + __expf(-x)); }

struct B3 { f16x8 r, z, n; };
// W row-major [1536][K]; rows g*512 + j (plain cached loads — weights stay hot, never invalidated)
__device__ __forceinline__ B3 ldB(const _Float16* __restrict__ W, int K, int row0, int koff) {
  B3 o;
  const _Float16* p = W + (size_t)row0 * K + koff;
  o.r = *(const f16x8*)p;
  o.z = *(const f16x8*)(p + (size_t)512 * K);
  o.n = *(const f16x8*)(p + (size_t)1024 * K);
  return o;
}

__device__ __forceinline__ f16x8 frag(const unsigned long long* hA, int c) {
  union { unsigned long long u[2]; f16x8 v; } x;
  x.u[0] = hA[2 * c]; x.u[1] = hA[2 * c + 1];
  return x.v;
}

__global__ void prep_x0(const int* __restrict__ texts, const float* __restrict__ emb,
                        _Float16* __restrict__ x0) {
  const size_t N = (size_t)T_STEPS * BB * EP;
  const size_t stride = (size_t)gridDim.x * blockDim.x;
  for (size_t i = (size_t)blockIdx.x * blockDim.x + threadIdx.x; i < N; i += stride) {
    int e = (int)(i % EP);
    size_t tb = i / EP;
    float v = 0.f;
    if (e < EE) v = emb[(size_t)texts[tb] * EE + e];
    x0[i] = (_Float16)v;
  }
}

__global__ void prep_w(const float* __restrict__ Wih0, const float* __restrict__ Whh0,
                       const float* __restrict__ bih0, const float* __restrict__ bhh0,
                       const float* __restrict__ Wih1, const float* __restrict__ Whh1,
                       const float* __restrict__ bih1, const float* __restrict__ bhh1,
                       _Float16* __restrict__ W0x, _Float16* __restrict__ W0h,
                       _Float16* __restrict__ W1x, _Float16* __restrict__ W1h,
                       float* __restrict__ bias0, float* __restrict__ bias1) {
  const size_t stride = (size_t)gridDim.x * blockDim.x;
  const size_t gid = (size_t)blockIdx.x * blockDim.x + threadIdx.x;
  for (size_t i = gid; i < (size_t)G3 * EP; i += stride) {
    int k = (int)(i % EP); int n = (int)(i / EP);
    W0x[i] = (k < EE) ? (_Float16)Wih0[(size_t)n * EE + k] : (_Float16)0.f;
  }
  for (size_t i = gid; i < (size_t)G3 * HH; i += stride) {
    W0h[i] = (_Float16)Whh0[i];
    W1x[i] = (_Float16)Wih1[i];
    W1h[i] = (_Float16)Whh1[i];
  }
  for (size_t i = gid; i < (size_t)HH; i += stride) {
    bias0[i]        = bih0[i] + bhh0[i];
    bias0[512 + i]  = bih0[512 + i] + bhh0[512 + i];
    bias0[1024 + i] = bih0[1024 + i];
    bias0[1536 + i] = bhh0[1024 + i];
    bias1[i]        = bih1[i] + bhh1[i];
    bias1[512 + i]  = bih1[512 + i] + bhh1[512 + i];
    bias1[1024 + i] = bih1[1024 + i];
    bias1[1536 + i] = bhh1[1024 + i];
  }
}

// 64 WGs x 256 threads. WG 0..31 = layer0 (j-chunks), 32..63 = layer1.
// Decoupled per-layer wave barriers: arrive0[s] (L0 publishes h1[s], 128 waves),
// arrive1[t] (L1 publishes h2[t]). h1 is a 4-slot ring so L0 runs ahead of L1.
__global__ __launch_bounds__(256, 1) void gru_persistent(
    const _Float16* __restrict__ x0,
    const _Float16* __restrict__ W0x, const _Float16* __restrict__ W0h,
    const _Float16* __restrict__ W1x, const _Float16* __restrict__ W1h,
    const float* __restrict__ bias0, const float* __restrict__ bias1,
    _Float16* h1ring, _Float16* h2buf, float* pooled,
    int* arrive0, int* arrive1)
{
  const int wg   = blockIdx.x;
  const int L    = wg >> 5;
  const int jb   = (wg & 31) * 16;
  const int tid  = threadIdx.x;
  const int bsub = tid >> 6;
  const int lane = tid & 63;
  const int quad = lane >> 4;
  const int l15  = lane & 15;
  const int brow = bsub * 16 + l15;   // A-operand row (batch)
  const int j    = jb + l15;          // output column
  const int koff = quad * 8;

  __shared__ _Float16 tile[2][64][16];   // parity-double-buffered h tile (b x j)

  if (L == 0) {
    const float br = bias0[j], bz = bias0[512 + j];
    const float bnx = bias0[1024 + j], bnh = bias0[1536 + j];
    f16x8 xpf[10];
    {
      const _Float16* xr = x0 + (size_t)brow * EP;
      #pragma unroll
      for (int c = 0; c < 10; ++c) xpf[c] = *(const f16x8*)(xr + c * 32 + koff);
      MEMBAR();
    }
    for (int s = 0; s < T_STEPS; ++s) {
      f32x4 aR = {0.f,0.f,0.f,0.f}, aZ = {0.f,0.f,0.f,0.f};
      f32x4 aNX = {0.f,0.f,0.f,0.f}, aNH = {0.f,0.f,0.f,0.f};
      // x-part: no cross-WG dependency — run before any spin
      #pragma unroll 5
      for (int c = 0; c < 10; ++c) {
        B3 bb = ldB(W0x, EP, j, c * 32 + koff);
        aR = mf(xpf[c], bb.r, aR); aZ = mf(xpf[c], bb.z, aZ); aNX = mf(xpf[c], bb.n, aNX);
      }
      // ring throttle: slot s%4 holds h1[s-4]; L1 must have consumed it (stage s-4 done)
      if (s >= RING) spin_ge(arrive1 + (s - RING), 128);
      if (s >= 1) {
        spin_ge(arrive0 + (s - 1), 128);
        const _Float16* hprev = h1ring + ((s - 1) & (RING - 1)) * HB;
        const unsigned long long* hq =
            (const unsigned long long*)(hprev + brow * HH) + quad * 2;
        unsigned long long hA[32];
        #pragma unroll
        for (int c = 0; c < 16; ++c) {       // all 32 LLC loads issue back-to-back
          hA[2*c]   = ld8_llc(hq + c * 8);
          hA[2*c+1] = ld8_llc(hq + c * 8 + 1);
        }
        MEMBAR();                            // forbid sinking loads into MFMA loop
        #pragma unroll 4
        for (int c = 0; c < 16; ++c) {
          f16x8 a = frag(hA, c);
          B3 bb = ldB(W0h, HH, j, c * 32 + koff);
          aR = mf(a, bb.r, aR); aZ = mf(a, bb.z, aZ); aNH = mf(a, bb.n, aNH);
        }
      }
      _Float16* tc = &tile[s & 1][0][0];
      const _Float16* tp = &tile[(s + 1) & 1][0][0];
      #pragma unroll
      for (int rg = 0; rg < 4; ++rg) {
        const int b = bsub * 16 + quad * 4 + rg;   // C/D row = quad*4+reg
        float r = sigf(aR[rg] + br);
        float z = sigf(aZ[rg] + bz);
        float n = tanhf(aNX[rg] + bnx + r * (aNH[rg] + bnh));
        float hp = (s >= 1) ? (float)tp[b * 16 + l15] : 0.f;  // prev h from LDS tile
        tc[b * 16 + l15] = (_Float16)((1.f - z) * n + z * hp);
      }
      __syncthreads();
      if (tid < 128) {                       // coalesced 16B bypass stores of h1[s]
        const int row = tid >> 1, seg = tid & 1;
        f16x8 v = *(const f16x8*)&tc[row * 16 + seg * 8];
        st16_llc(h1ring + (s & (RING - 1)) * HB + row * HH + jb + seg * 8, v);
      }
      __builtin_amdgcn_s_waitcnt(0);         // hand-rolled release: stores at LLC
      if ((tid & 63) == 0)
        __hip_atomic_fetch_add(arrive0 + s, 1, __ATOMIC_RELAXED, __HIP_MEMORY_SCOPE_AGENT);
      {
        const int sn = (s + 1 < T_STEPS) ? s + 1 : s;  // prefetch next x behind barrier
        const _Float16* xr = x0 + ((size_t)sn * BB + brow) * EP;
        #pragma unroll
        for (int c = 0; c < 10; ++c) xpf[c] = *(const f16x8*)(xr + c * 32 + koff);
        MEMBAR();
      }
    }
  } else {
    const float br = bias1[j], bz = bias1[512 + j];
    const float bnx = bias1[1024 + j], bnh = bias1[1536 + j];
    for (int t = 0; t < T_STEPS; ++t) {
      f32x4 aR = {0.f,0.f,0.f,0.f}, aZ = {0.f,0.f,0.f,0.f};
      f32x4 aNX = {0.f,0.f,0.f,0.f}, aNH = {0.f,0.f,0.f,0.f};
      spin_ge(arrive0 + t, 128);             // h1[t] published by L0
      {
        const _Float16* a1p = h1ring + (t & (RING - 1)) * HB;
        const unsigned long long* aq =
            (const unsigned long long*)(a1p + brow * HH) + quad * 2;
        unsigned long long A1[32];
        #pragma unroll
        for (int c = 0; c < 16; ++c) {
          A1[2*c]   = ld8_llc(aq + c * 8);
          A1[2*c+1] = ld8_llc(aq + c * 8 + 1);
        }
        MEMBAR();
        #pragma unroll 4
        for (int c = 0; c < 16; ++c) {
          f16x8 a = frag(A1, c);
          B3 bb = ldB(W1x, HH, j, c * 32 + koff);
          aR = mf(a, bb.r, aR); aZ = mf(a, bb.z, aZ); aNX = mf(a, bb.n, aNX);
        }
      }
      if (t >= 1) {
        spin_ge(arrive1 + (t - 1), 128);     // h2[t-1] published (self-recurrence)
        const _Float16* a2p = h2buf + ((t - 1) & 1) * HB;
        const unsigned long long* aq =
            (const unsigned long long*)(a2p + brow * HH) + quad * 2;
        unsigned long long A2[32];
        #pragma unroll
        for (int c = 0; c < 16; ++c) {
          A2[2*c]   = ld8_llc(aq + c * 8);
          A2[2*c+1] = ld8_llc(aq + c * 8 + 1);
        }
        MEMBAR();
        #pragma unroll 4
        for (int c = 0; c < 16; ++c) {
          f16x8 a = frag(A2, c);
          B3 bb = ldB(W1h, HH, j, c * 32 + koff);
          aR = mf(a, bb.r, aR); aZ = mf(a, bb.z, aZ); aNH = mf(a, bb.n, aNH);
        }
      }
      _Float16* tc = &tile[t & 1][0][0];
      const _Float16* tp = &tile[(t + 1) & 1][0][0];
      #pragma unroll
      for (int rg = 0; rg < 4; ++rg) {
        const int b = bsub * 16 + quad * 4 + rg;
        float r = sigf(aR[rg] + br);
        float z = sigf(aZ[rg] + bz);
        float n = tanhf(aNX[rg] + bnx + r * (aNH[rg] + bnh));
        float hp = (t >= 1) ? (float)tp[b * 16 + l15] : 0.f;
        tc[b * 16 + l15] = (_Float16)((1.f - z) * n + z * hp);
      }
      __syncthreads();
      if (tid < 128) {
        const int row = tid >> 1, seg = tid & 1;
        f16x8 v = *(const f16x8*)&tc[row * 16 + seg * 8];
        st16_llc(h2buf + (t & 1) * HB + row * HH + jb + seg * 8, v);
      } else if (tid < 144) {                // batch-mean partial: column sum of tile
        const int u = tid - 128;
        float sum = 0.f;
        #pragma unroll 8
        for (int rr = 0; rr < 64; ++rr) sum += (float)tc[rr * 16 + u];
        pooled[(size_t)t * HH + jb + u] = sum;   // raw sum over b; /64 in FC
      }
      __builtin_amdgcn_s_waitcnt(0);
      if ((tid & 63) == 0)
        __hip_atomic_fetch_add(arrive1 + t, 1, __ATOMIC_RELAXED, __HIP_MEMORY_SCOPE_AGENT);
    }
  }
}

__global__ void fc_kernel(const float* __restrict__ pooled, const float* __restrict__ fcW,
                          const float* __restrict__ fcb, float* __restrict__ out) {
  const int t = blockIdx.x;
  const int lane = threadIdx.x;  // 64 = one wave
  float a0 = 0.f, a1 = 0.f, a2 = 0.f, a3 = 0.f, a4 = 0.f;
  for (int jj = lane; jj < HH; jj += 64) {
    float p = pooled[(size_t)t * HH + jj];
    a0 += p * fcW[jj];
    a1 += p * fcW[512 + jj];
    a2 += p * fcW[1024 + jj];
    a3 += p * fcW[1536 + jj];
    a4 += p * fcW[2048 + jj];
  }
  #pragma unroll
  for (int off = 32; off > 0; off >>= 1) {
    a0 += __shfl_down(a0, off, 64);
    a1 += __shfl_down(a1, off, 64);
    a2 += __shfl_down(a2, off, 64);
    a3 += __shfl_down(a3, off, 64);
    a4 += __shfl_down(a4, off, 64);
  }
  if (lane == 0) {
    const float sc = 1.f / 64.f;
    out[t * 5 + 0] = a0 * sc + fcb[0];
    out[t * 5 + 1] = a1 * sc + fcb[1];
    out[t * 5 + 2] = a2 * sc + fcb[2];
    out[t * 5 + 3] = a3 * sc + fcb[3];
    out[t * 5 + 4] = a4 * sc + fcb[4];
  }
}

extern "C" void kernel_launch(void* const* d_in, const int* in_sizes, int n_in,
                              void* d_out, int out_size, void* d_ws, size_t ws_size,
                              hipStream_t stream) {
  const int*   texts = (const int*)  d_in[0];
  const float* emb   = (const float*)d_in[1];
  const float* Wih0  = (const float*)d_in[2];
  const float* Whh0  = (const float*)d_in[3];
  const float* bih0  = (const float*)d_in[4];
  const float* bhh0  = (const float*)d_in[5];
  const float* Wih1  = (const float*)d_in[6];
  const float* Whh1  = (const float*)d_in[7];
  const float* bih1  = (const float*)d_in[8];
  const float* bhh1  = (const float*)d_in[9];
  const float* fcW   = (const float*)d_in[10];
  const float* fcb   = (const float*)d_in[11];
  float* out = (float*)d_out;

  char* ws = (char*)d_ws;
  int*      arrive0 = (int*)ws;                       // 2048 B (512 ints)
  int*      arrive1 = (int*)(ws + 2048);              // 2048 B
  _Float16* h1ring  = (_Float16*)(ws + 8192);         // 262144 B (4 x 64x512 f16)
  _Float16* h2buf   = (_Float16*)(ws + 270336);       // 131072 B (2 slots)
  _Float16* x0      = (_Float16*)(ws + 401408);       // 20971520 B [512][64][320]
  _Float16* W0x     = (_Float16*)(ws + 21372928);     // 983040 B  [1536][320]
  _Float16* W0h     = (_Float16*)(ws + 22355968);     // 1572864 B [1536][512]
  _Float16* W1x     = (_Float16*)(ws + 23928832);     // 1572864 B
  _Float16* W1h     = (_Float16*)(ws + 25501696);     // 1572864 B
  float*    bias0   = (float*)(ws + 27074560);        // 8192 B (r,z,nx,nh)
  float*    bias1   = (float*)(ws + 27082752);        // 8192 B
  float*    pooled  = (float*)(ws + 27090944);        // 1048576 B [512][512] f32
  // total ws use: 28139520 B

  hipMemsetAsync(ws, 0, 8192, stream);  // arrive0 + arrive1 = zeros
  prep_x0<<<4096, 256, 0, stream>>>(texts, emb, x0);
  prep_w<<<1024, 256, 0, stream>>>(Wih0, Whh0, bih0, bhh0, Wih1, Whh1, bih1, bhh1,
                                   W0x, W0h, W1x, W1h, bias0, bias1);
  gru_persistent<<<64, 256, 0, stream>>>(x0, W0x, W0h, W1x, W1h, bias0, bias1,
                                         h1ring, h2buf, pooled, arrive0, arrive1);
  fc_kernel<<<512, 64, 0, stream>>>(pooled, fcW, fcb, out);
}